// Round 16
// baseline (111.879 us; speedup 1.0000x reference)
//
#include <hip/hip_runtime.h>
#include <hip/hip_bf16.h>

// EnTransformerBlock, MFMA v16: 4-wave blocks (256 thr), 32-sender tiles,
// 25.6KB LDS -> 6 blocks/CU, uncapped VGPR, hoisted loop-invariant frags.
// N=512, V=8, F=128, H=8, FH=16, B=8. Dense all-pairs edges.
//
// ws layout (float offsets):
//   knB  @ 0       bf16[512][128]      (feat@Wk)
//   vnT  @ 32768   bf16[128][512]      (feat@Wv transposed)
//   qnB  @ 65536   bf16[512][128]      (0.25 * feat@Wq)
//   A4T  @ 98304   bf16[512][8][128]   (0.25 * Wek-folded-q)
//   WgT  @ 360448  bf16[8][128]        (Wg transposed)
//   W0T  @ 360960  bf16[128][64]
//   W1T  @ 365056  bf16[128][128]
//   PS   @ 373248  [2048][1072] partial state
#define WS_KNB  0
#define WS_VNT  32768
#define WS_QNB  65536
#define WS_A4T  98304
#define WS_WGT  360448
#define WS_W0T  360960
#define WS_W1T  365056
#define WS_PS   373248
#define PS_STRIDE 1072

typedef short bf16x8 __attribute__((ext_vector_type(8)));
typedef short short4v __attribute__((ext_vector_type(4)));
typedef float f32x4 __attribute__((ext_vector_type(4)));
typedef unsigned short ushort_t;

static __device__ __forceinline__ ushort_t f2b(float x) {
  __hip_bfloat16 h = __float2bfloat16(x);
  return reinterpret_cast<ushort_t&>(h);
}
static __device__ __forceinline__ unsigned pk2(float a, float b) {
  __hip_bfloat162 t = __float22bfloat162_rn(make_float2(a, b));
  return reinterpret_cast<unsigned&>(t);
}
static __device__ __forceinline__ float b2f(ushort_t u) {
  unsigned v = ((unsigned)u) << 16;
  return reinterpret_cast<float&>(v);
}
static __device__ __forceinline__ float fsilu(float x) {
  return x * __builtin_amdgcn_rcpf(1.f + __expf(-x));
}

static __device__ __forceinline__ bf16x8 radial_frag(
    float dx, float dy, float dz, float& ux, float& uy, float& uz)
{
  const float l2 = fmaf(dx,dx, fmaf(dy,dy, fmaf(dz,dz, 1e-20f)));
  const float inv = rsqrtf(l2);
  const float len = l2 * inv;
  ux = dx*inv; uy = dy*inv; uz = dz*inv;
  const float yy = 2.f - len*0.2f;
  const float env = (yy > 0.f) ? 1.9784655648f * __expf(-__builtin_amdgcn_rcpf(yy)) : 0.f;
  const float coef = 0.4472135955f * env * inv;
  const float arg = len * 0.31415926535f;
  const float s1v = __sinf(arg), c1v = __cosf(arg);
  const float twc = 2.f*c1v;
  float sp = 0.f, sc = s1v;
  float e[8];
#pragma unroll
  for (int bb = 0; bb < 8; ++bb) {
    e[bb] = coef*sc;
    const float nx = fmaf(twc, sc, -sp);
    sp = sc; sc = nx;
  }
  union { bf16x8 v8; unsigned u4[4]; } pk;
#pragma unroll
  for (int q = 0; q < 4; ++q) pk.u4[q] = pk2(e[2*q], e[2*q+1]);
  return pk.v8;
}

// blocks 0..511: per-node prep; 512..703: weight transposes
__global__ __launch_bounds__(128) void k_prep(
    const float* __restrict__ feat, const float* __restrict__ Wq,
    const float* __restrict__ Wk, const float* __restrict__ Wv,
    const float* __restrict__ Wek, const float* __restrict__ Wg,
    const float* __restrict__ We0, const float* __restrict__ We1,
    float* __restrict__ ws)
{
  const int blk = blockIdx.x, j = threadIdx.x;
  if (blk >= 512) {
    const int i = (blk - 512)*128 + j;
    ushort_t* W0T = (ushort_t*)(ws + WS_W0T);
    ushort_t* W1T = (ushort_t*)(ws + WS_W1T);
    if (i < 8192) {
      const int n = i >> 6, k = i & 63;
      W0T[n*64 + k] = f2b(We0[k*128 + n]);
    } else {
      const int t = i - 8192, n = t >> 7, k = t & 127;
      W1T[n*128 + k] = f2b(We1[k*128 + n]);
    }
    return;
  }
  const int r = blk;
  __shared__ float fr[128];
  __shared__ float qL[128];
  fr[j] = feat[r*128 + j];
  __syncthreads();
  float aq = 0.f, ak = 0.f, av = 0.f;
#pragma unroll 4
  for (int i = 0; i < 128; ++i) {
    const float f = fr[i];
    aq = fmaf(f, Wq[i*128 + j], aq);
    ak = fmaf(f, Wk[i*128 + j], ak);
    av = fmaf(f, Wv[i*128 + j], av);
  }
  ushort_t* knB = (ushort_t*)(ws + WS_KNB);
  ushort_t* vnT = (ushort_t*)(ws + WS_VNT);
  ushort_t* qnB = (ushort_t*)(ws + WS_QNB);
  knB[r*128 + j] = f2b(ak);
  vnT[j*512 + r] = f2b(av);
  qnB[r*128 + j] = f2b(0.25f * aq);
  qL[j] = aq;
  __syncthreads();
  ushort_t* A4 = (ushort_t*)(ws + WS_A4T) + r*1024;
  const float* wr = Wek + j*128;
#pragma unroll
  for (int h = 0; h < 8; ++h) {
    float acc = 0.f;
#pragma unroll
    for (int f = 0; f < 16; ++f)
      acc = fmaf(wr[16*h + f], qL[16*h + f], acc);
    A4[h*128 + j] = f2b(acc * 0.25f);
  }
  if (r == 0) {
    ushort_t* WgT = (ushort_t*)(ws + WS_WGT);
#pragma unroll
    for (int v = 0; v < 8; ++v)
      WgT[v*128 + j] = f2b(Wg[j*8 + v]);
  }
}

// LDS (25632 B):
//   H1   @ 0      bf16[32][128] 8192  swz: row*128 + (((ncol>>3)^(row&15))<<3)+(c&7)
//   H2t  @ 8192   bf16[128][32] 8192  elem(f,s): f*32 + (((s>>3)^CSW(f))&3)*8 + (s&7)
//                                     CSW(f) = (f&3)^((f>>2)&3)
//   Es   @ 16384  bf16[32][64]  4096  elem(sl, v*8+b): sl*64 + ((v^(sl&7))<<3)+b
//   lgT0 @ 20480  f32[16][32]   2048
//   lgT1 @ 22528  f32[16][32]   2048
//   Pb   @ 24576  bf16[16][32]  1024  elem(ch,s): ch*32 + (((s>>3)^(ch&3))&3)*8+(s&7)
//   rscL @ 25600  f32[8]          32
#define MFMA(a,b,c) __builtin_amdgcn_mfma_f32_16x16x32_bf16((a),(b),(c),0,0,0)

__global__ __launch_bounds__(256) void k_edge16(
    const float* __restrict__ pos,
    const float* __restrict__ be0, const float* __restrict__ be1,
    float* __restrict__ ws)
{
  __shared__ __align__(16) char Lds[25632];
  ushort_t* H1   = (ushort_t*)(Lds);
  ushort_t* H2t  = (ushort_t*)(Lds + 8192);
  ushort_t* Es   = (ushort_t*)(Lds + 16384);
  float*    lgT0 = (float*)(Lds + 20480);
  float*    lgT1 = (float*)(Lds + 22528);
  ushort_t* Pb   = (ushort_t*)(Lds + 24576);
  float*    rscL = (float*)(Lds + 25600);

  const int tid = threadIdx.x;
  const int nw = tid >> 6, l = tid & 63;
  const int c = l & 15, g = l >> 4;
  const int b = blockIdx.x;
  const int r = b >> 2, quarter = b & 3;
  const int base = quarter * 128;

  const ushort_t* knB = (const ushort_t*)(ws + WS_KNB);
  const ushort_t* vnT = (const ushort_t*)(ws + WS_VNT);
  const ushort_t* qnB = (const ushort_t*)(ws + WS_QNB);
  const ushort_t* A4G = (const ushort_t*)(ws + WS_A4T) + r*1024;
  const ushort_t* WgG = (const ushort_t*)(ws + WS_WGT);
  const ushort_t* W0T = (const ushort_t*)(ws + WS_W0T);
  const ushort_t* W1T = (const ushort_t*)(ws + WS_W1T);

  // wave columns: 2 n-tiles of 16
  const int ncol0 = nw*32 + c, ncol1 = nw*32 + 16 + c;
  const float be00 = be0[ncol0], be01 = be0[ncol1];
  const float be10 = be1[ncol0], be11 = be1[ncol1];
  const int csw0 = ((ncol0 & 3) ^ ((ncol0 >> 2) & 3)) & 3;
  const int csw1 = ((ncol1 & 3) ^ ((ncol1 >> 2) & 3)) & 3;
  const int m_lg = nw & 1, kh = nw >> 1;

  // loop-invariant fragments
  const bf16x8 w0f00 = *(const bf16x8*)(W0T + ncol0*64 + g*8);
  const bf16x8 w0f01 = *(const bf16x8*)(W0T + ncol0*64 + 32 + g*8);
  const bf16x8 w0f10 = *(const bf16x8*)(W0T + ncol1*64 + g*8);
  const bf16x8 w0f11 = *(const bf16x8*)(W0T + ncol1*64 + 32 + g*8);
  bf16x8 awf[4];
  if (kh == 0) {
    const ushort_t* ab = (c < 8) ? (A4G + c*128) : (WgG + (c-8)*128);
#pragma unroll
    for (int kb = 0; kb < 4; ++kb)
      awf[kb] = *(const bf16x8*)(ab + kb*32 + g*8);
  } else {
#pragma unroll
    for (int kb = 0; kb < 4; ++kb) {
      const bf16x8 qf = *(const bf16x8*)(qnB + r*128 + kb*32 + g*8);
      const bool hit = (kb*2 + (g>>1)) == c;
#pragma unroll
      for (int j = 0; j < 8; ++j) awf[kb][j] = hit ? qf[j] : (short)0;
    }
  }

  // geometry identity: lane -> (sender sl = l&31, vector v = nw*2 + (l>>5))
  const int gsl = l & 31, gv = nw*2 + (l >> 5);
  const float prx = pos[r*24 + gv*3 + 0];
  const float pry = pos[r*24 + gv*3 + 1];
  const float prz = pos[r*24 + gv*3 + 2];

  f32x4 bh0 = {0,0,0,0}, bh1 = {0,0,0,0};
  f32x4 sn0 = {0,0,0,0}, sn1 = {0,0,0,0};
  float avx = 0.f, avy = 0.f, avz = 0.f;
  float mrun = -1e30f, drun = 0.f;
  float ux, uy, uz;

  // prologue: geometry tile 0 -> Es
  {
    const int sg = base + gsl;
    const bf16x8 ev = radial_frag(pos[sg*24 + gv*3 + 0] - prx,
                                  pos[sg*24 + gv*3 + 1] - pry,
                                  pos[sg*24 + gv*3 + 2] - prz, ux, uy, uz);
    *(bf16x8*)(Es + gsl*64 + ((gv ^ (gsl&7))<<3)) = ev;
  }
  __syncthreads();

  for (int tile = 0; tile < 4; ++tile) {
    const int gbase = base + tile*32;

    float npx = 0.f, npy = 0.f, npz = 0.f;
    if (tile < 3) {
      const int sg = gbase + 32 + gsl;
      npx = pos[sg*24 + gv*3 + 0];
      npy = pos[sg*24 + gv*3 + 1];
      npz = pos[sg*24 + gv*3 + 2];
    }

    // ---- s0: L0 (Es[32][64] @ We0 -> H1[32][128]) ----
#pragma unroll
    for (int m = 0; m < 2; ++m) {
      const int ra = m*16 + c;
      const bf16x8 e0 = *(const bf16x8*)(Es + ra*64 + (((g  ) ^ (ra&7))<<3));
      const bf16x8 e1 = *(const bf16x8*)(Es + ra*64 + (((4+g) ^ (ra&7))<<3));
      f32x4 a0 = {0,0,0,0}, a1 = {0,0,0,0};
      a0 = MFMA(e0, w0f00, a0); a0 = MFMA(e1, w0f01, a0);
      a1 = MFMA(e0, w0f10, a1); a1 = MFMA(e1, w0f11, a1);
#pragma unroll
      for (int i = 0; i < 4; ++i) {
        const int row = m*16 + g*4 + i;
        H1[row*128 + (((ncol0>>3) ^ (row&15))<<3) + (c&7)] = f2b(fsilu(a0[i] + be00));
        H1[row*128 + (((ncol1>>3) ^ (row&15))<<3) + (c&7)] = f2b(fsilu(a1[i] + be01));
      }
    }
    __syncthreads();  // B: H1 ready (Es consumed)

    // ---- s1: prefetch knf; L1 (H1 @ We1) silu -> H2t ----
    bf16x8 knf[4];
    if (kh == 1) {
      const int srow = gbase + m_lg*16 + c;
#pragma unroll
      for (int kb = 0; kb < 4; ++kb)
        knf[kb] = *(const bf16x8*)(knB + srow*128 + kb*32 + g*8);
    }
#pragma unroll
    for (int m = 0; m < 2; ++m) {
      const int ra = m*16 + c;
      bf16x8 af[4];
#pragma unroll
      for (int kb = 0; kb < 4; ++kb)
        af[kb] = *(const bf16x8*)(H1 + ra*128 + (((kb*4+g) ^ (ra&15))<<3));
      f32x4 a0 = {0,0,0,0}, a1 = {0,0,0,0};
#pragma unroll
      for (int kb = 0; kb < 4; ++kb) {
        a0 = MFMA(af[kb], *(const bf16x8*)(W1T + ncol0*128 + kb*32 + g*8), a0);
        a1 = MFMA(af[kb], *(const bf16x8*)(W1T + ncol1*128 + kb*32 + g*8), a1);
      }
      const int chnk = m*2 + (g>>1);
      union { short4v v4; unsigned u2[2]; } p0, p1;
      p0.u2[0] = pk2(fsilu(a0[0] + be10), fsilu(a0[1] + be10));
      p0.u2[1] = pk2(fsilu(a0[2] + be10), fsilu(a0[3] + be10));
      p1.u2[0] = pk2(fsilu(a1[0] + be11), fsilu(a1[1] + be11));
      p1.u2[1] = pk2(fsilu(a1[2] + be11), fsilu(a1[3] + be11));
      *(short4v*)(H2t + ncol0*32 + (((chnk ^ csw0) & 3)<<3) + (g&1)*4) = p0.v4;
      *(short4v*)(H2t + ncol1*32 + (((chnk ^ csw1) & 3)<<3) + (g&1)*4) = p1.v4;
    }
    __syncthreads();  // C: H2t ready (H1 consumed)

    // ---- s2: LG K=256 split -> lgT[ch][sender] ----
    {
      f32x4 lg = {0,0,0,0};
      if (kh == 0) {
        const int sb = m_lg*2 + (c>>3);   // sender>>3
        const int si = c & 7;             // sender&7
#pragma unroll
        for (int kb = 0; kb < 4; ++kb) {
          bf16x8 bb;
#pragma unroll
          for (int j = 0; j < 8; ++j) {
            const int f = kb*32 + g*8 + j;
            bb[j] = (short)H2t[f*32 + (((sb ^ (f&3) ^ ((f>>2)&3)) & 3)<<3) + si];
          }
          lg = MFMA(awf[kb], bb, lg);
        }
      } else {
#pragma unroll
        for (int kb = 0; kb < 4; ++kb)
          lg = MFMA(awf[kb], knf[kb], lg);
      }
      float* lgW = kh ? lgT1 : lgT0;
#pragma unroll
      for (int i = 0; i < 4; ++i)
        lgW[(g*4 + i)*32 + m_lg*16 + c] = lg[i];
    }
    __syncthreads();  // S1: lgT ready

    // ---- s3: softmax (2 heads/wave, 32-lane halves) + equivariant accum ----
    {
      const int h = gv;         // head = vector = nw*2 + (l>>5)
      const int sl = gsl;
      float lgv = lgT0[h*32 + sl] + lgT1[h*32 + sl];
      const float gate = lgT0[(8+h)*32 + sl] + lgT1[(8+h)*32 + sl];
      if (gbase + sl == r) lgv = -1e30f;
      float t = lgv;
      t = fmaxf(t, __shfl_xor(t, 1));
      t = fmaxf(t, __shfl_xor(t, 2));
      t = fmaxf(t, __shfl_xor(t, 4));
      t = fmaxf(t, __shfl_xor(t, 8));
      t = fmaxf(t, __shfl_xor(t, 16));
      const float mnew = fmaxf(mrun, t);
      const float rsc = __expf(mrun - mnew);
      mrun = mnew;
      const float val = __expf(lgv - mnew);
      float wsm = val;
      wsm += __shfl_xor(wsm, 1);
      wsm += __shfl_xor(wsm, 2);
      wsm += __shfl_xor(wsm, 4);
      wsm += __shfl_xor(wsm, 8);
      wsm += __shfl_xor(wsm, 16);
      drun = drun*rsc + wsm;
      const float ga = val * gate;
      Pb[h*32 + ((((sl>>3) ^ (h&3)) & 3)<<3) + (sl&7)] = f2b(val);
      Pb[(8+h)*32 + ((((sl>>3) ^ ((8+h)&3)) & 3)<<3) + (sl&7)] = f2b(ga);
      if (sl == 0) rscL[h] = rsc;
      avx = avx*rsc + ga*ux;
      avy = avy*rsc + ga*uy;
      avz = avz*rsc + ga*uz;
    }
    __syncthreads();  // S2: Pb/rscL ready

    // ---- s4: rescale + P-MFMAs (K=32) + geometry(t+1) -> Es ----
    {
      float rs[4];
#pragma unroll
      for (int i = 0; i < 4; ++i) rs[i] = rscL[(4*g + i) & 7];
#pragma unroll
      for (int i = 0; i < 4; ++i) {
        bh0[i] *= rs[i]; bh1[i] *= rs[i];
        sn0[i] *= rs[i]; sn1[i] *= rs[i];
      }
      const bf16x8 pa = *(const bf16x8*)(Pb + c*32 + (((g ^ (c&3)) & 3)<<3));
      bh0 = MFMA(pa, *(const bf16x8*)(H2t + ncol0*32 + (((g ^ csw0) & 3)<<3)), bh0);
      bh1 = MFMA(pa, *(const bf16x8*)(H2t + ncol1*32 + (((g ^ csw1) & 3)<<3)), bh1);
      sn0 = MFMA(pa, *(const bf16x8*)(vnT + ncol0*512 + gbase + g*8), sn0);
      sn1 = MFMA(pa, *(const bf16x8*)(vnT + ncol1*512 + gbase + g*8), sn1);
    }
    if (tile < 3) {
      const bf16x8 ev = radial_frag(npx - prx, npy - pry, npz - prz, ux, uy, uz);
      *(bf16x8*)(Es + gsl*64 + ((gv ^ (gsl&7))<<3)) = ev;
      __syncthreads();  // E: Es(t+1) ready; protects Pb/lgT rewrite
    }
  }

  // ---- write partial state ----
  float* PSf = ws + WS_PS + b*PS_STRIDE;
  ushort_t* PSs = (ushort_t*)PSf;
  if (g < 2) {
#pragma unroll
    for (int i = 0; i < 4; ++i) {
      PSs[(4*g + i)*128 + ncol0] = f2b(bh0[i]);
      PSs[(4*g + i)*128 + ncol1] = f2b(bh1[i]);
      PSs[1024 + (4*g + i)*128 + ncol0] = f2b(sn0[i]);
      PSs[1024 + (4*g + i)*128 + ncol1] = f2b(sn1[i]);
    }
  }
  avx += __shfl_xor(avx, 1); avy += __shfl_xor(avy, 1); avz += __shfl_xor(avz, 1);
  avx += __shfl_xor(avx, 2); avy += __shfl_xor(avy, 2); avz += __shfl_xor(avz, 2);
  avx += __shfl_xor(avx, 4); avy += __shfl_xor(avy, 4); avz += __shfl_xor(avz, 4);
  avx += __shfl_xor(avx, 8); avy += __shfl_xor(avy, 8); avz += __shfl_xor(avz, 8);
  avx += __shfl_xor(avx,16); avy += __shfl_xor(avy,16); avz += __shfl_xor(avz,16);
  if (gsl == 0) {
    PSf[1024 + gv*3 + 0] = avx;
    PSf[1024 + gv*3 + 1] = avy;
    PSf[1024 + gv*3 + 2] = avz;
    PSf[1048 + gv] = mrun;
    PSf[1056 + gv] = drun;
  }
}

__global__ __launch_bounds__(128) void k_merge(
    const float* __restrict__ pos, const float* __restrict__ feat,
    const float* __restrict__ Wev,
    const float* __restrict__ Wo0, const float* __restrict__ bo0,
    const float* __restrict__ Wo1, const float* __restrict__ bo1,
    const float* __restrict__ Wo2, const float* __restrict__ bo2,
    const float* __restrict__ ws, float* __restrict__ out)
{
  const int r = blockIdx.x, j = threadIdx.x;
  __shared__ float Ss[32], Dh[8];
  __shared__ float BhC[1024];
  __shared__ float asB[128], o1[128], o2[128];
  const float* Pf[4];
  const ushort_t* Ps[4];
#pragma unroll
  for (int i = 0; i < 4; ++i) {
    Pf[i] = ws + WS_PS + (4*r + i)*PS_STRIDE;
    Ps[i] = (const ushort_t*)Pf[i];
  }
  if (j < 8) {
    float M = -1e30f;
#pragma unroll
    for (int i = 0; i < 4; ++i) M = fmaxf(M, Pf[i][1048 + j]);
    float D = 0.f;
#pragma unroll
    for (int i = 0; i < 4; ++i) {
      const float s = __expf(Pf[i][1048 + j] - M);
      Ss[i*8 + j] = s;
      D = fmaf(s, Pf[i][1056 + j], D);
    }
    Dh[j] = D;
  }
  __syncthreads();
#pragma unroll
  for (int h = 0; h < 8; ++h) {
    float acc = 0.f;
#pragma unroll
    for (int i = 0; i < 4; ++i)
      acc = fmaf(Ss[i*8 + h], b2f(Ps[i][h*128 + j]), acc);
    BhC[h*128 + j] = acc;
  }
  const int hh = j >> 4;
  float snj = 0.f;
#pragma unroll
  for (int i = 0; i < 4; ++i)
    snj = fmaf(Ss[i*8 + hh], b2f(Ps[i][1024 + hh*128 + j]), snj);
  if (j < 24) {
    const int v = j / 3;
    float avc = 0.f;
#pragma unroll
    for (int i = 0; i < 4; ++i)
      avc = fmaf(Ss[i*8 + v], Pf[i][1024 + j], avc);
    out[r*24 + j] = pos[r*24 + j]
        + 1.7320508076f * avc * __builtin_amdgcn_rcpf(Dh[v]);
  }
  __syncthreads();
  {
    float ev = 0.f;
#pragma unroll 4
    for (int m = 0; m < 128; ++m)
      ev = fmaf(BhC[hh*128 + m], Wev[m*128 + j], ev);
    asB[j] = (snj + ev) * __builtin_amdgcn_rcpf(Dh[hh]);
  }
  __syncthreads();
  {
    float acc = bo0[j];
#pragma unroll 4
    for (int i = 0; i < 128; ++i) acc = fmaf(asB[i], Wo0[i*128 + j], acc);
    o1[j] = fsilu(acc);
  }
  __syncthreads();
  {
    float acc = bo1[j];
#pragma unroll 4
    for (int i = 0; i < 128; ++i) acc = fmaf(o1[i], Wo1[i*128 + j], acc);
    o2[j] = fsilu(acc);
  }
  __syncthreads();
  {
    float acc = bo2[j];
#pragma unroll 4
    for (int i = 0; i < 128; ++i) acc = fmaf(o2[i], Wo2[i*128 + j], acc);
    out[12288 + r*128 + j] = feat[r*128 + j] + acc;
  }
}

extern "C" void kernel_launch(void* const* d_in, const int* in_sizes, int n_in,
                              void* d_out, int out_size, void* d_ws, size_t ws_size,
                              hipStream_t stream)
{
  const float* pos  = (const float*)d_in[0];
  const float* feat = (const float*)d_in[1];
  const float* We0  = (const float*)d_in[2];
  const float* be0  = (const float*)d_in[3];
  const float* We1  = (const float*)d_in[4];
  const float* be1  = (const float*)d_in[5];
  const float* Wq   = (const float*)d_in[6];
  const float* Wk   = (const float*)d_in[7];
  const float* Wek  = (const float*)d_in[8];
  const float* Wv   = (const float*)d_in[9];
  const float* Wev  = (const float*)d_in[10];
  const float* Wg   = (const float*)d_in[11];
  const float* Wo0  = (const float*)d_in[12];
  const float* bo0  = (const float*)d_in[13];
  const float* Wo1  = (const float*)d_in[14];
  const float* bo1  = (const float*)d_in[15];
  const float* Wo2  = (const float*)d_in[16];
  const float* bo2  = (const float*)d_in[17];
  float* ws  = (float*)d_ws;
  float* out = (float*)d_out;

  hipLaunchKernelGGL(k_prep, dim3(704), dim3(128), 0, stream,
                     feat, Wq, Wk, Wv, Wek, Wg, We0, We1, ws);
  hipLaunchKernelGGL(k_edge16, dim3(2048), dim3(256), 0, stream,
                     pos, be0, be1, ws);
  hipLaunchKernelGGL(k_merge, dim3(512), dim3(128), 0, stream,
                     pos, feat, Wev, Wo0, bo0, Wo1, bo1, Wo2, bo2, ws, out);
}

// Round 17
// 101.519 us; speedup vs baseline: 1.1021x; 1.1021x over previous
//
#include <hip/hip_runtime.h>
#include <hip/hip_bf16.h>

// EnTransformerBlock, MFMA v17 == v14 (best measured: 101.7 us).
// Quarter-sender split (grid 2048, 2 tiles/block), 8-wave blocks, 4-way merge.
// N=512, V=8, F=128, H=8, FH=16, B=8. Dense all-pairs edges.
//
// ws layout (float offsets):
//   knB  @ 0       bf16[512][128]      (feat@Wk)
//   vnT  @ 32768   bf16[128][512]      (feat@Wv transposed)
//   qnB  @ 65536   bf16[512][128]      (0.25 * feat@Wq)
//   A4T  @ 98304   bf16[512][8][128]   (0.25 * Wek-folded-q)
//   WgT  @ 360448  bf16[8][128]        (Wg transposed)
//   W0T  @ 360960  bf16[128][64]
//   W1T  @ 365056  bf16[128][128]
//   PS   @ 373248  [2048][1072] partial state
#define WS_KNB  0
#define WS_VNT  32768
#define WS_QNB  65536
#define WS_A4T  98304
#define WS_WGT  360448
#define WS_W0T  360960
#define WS_W1T  365056
#define WS_PS   373248
#define PS_STRIDE 1072

typedef short bf16x8 __attribute__((ext_vector_type(8)));
typedef short short4v __attribute__((ext_vector_type(4)));
typedef float f32x4 __attribute__((ext_vector_type(4)));
typedef unsigned short ushort_t;

static __device__ __forceinline__ ushort_t f2b(float x) {
  __hip_bfloat16 h = __float2bfloat16(x);
  return reinterpret_cast<ushort_t&>(h);
}
static __device__ __forceinline__ float b2f(ushort_t u) {
  unsigned v = ((unsigned)u) << 16;
  return reinterpret_cast<float&>(v);
}
static __device__ __forceinline__ float fsilu(float x) {
  return x * __builtin_amdgcn_rcpf(1.f + __expf(-x));
}

static __device__ __forceinline__ bf16x8 radial_frag(
    float dx, float dy, float dz, float& ux, float& uy, float& uz)
{
  const float l2 = fmaf(dx,dx, fmaf(dy,dy, fmaf(dz,dz, 1e-20f)));
  const float inv = rsqrtf(l2);
  const float len = l2 * inv;
  ux = dx*inv; uy = dy*inv; uz = dz*inv;
  const float yy = 2.f - len*0.2f;
  const float env = (yy > 0.f) ? 1.9784655648f * __expf(-__builtin_amdgcn_rcpf(yy)) : 0.f;
  const float coef = 0.4472135955f * env * inv;
  const float arg = len * 0.31415926535f;
  const float s1v = __sinf(arg), c1v = __cosf(arg);
  const float twc = 2.f*c1v;
  float sp = 0.f, sc = s1v;
  bf16x8 ev;
#pragma unroll
  for (int bb = 0; bb < 8; ++bb) {
    ev[bb] = (short)f2b(coef*sc);
    const float nx = fmaf(twc, sc, -sp);
    sp = sc; sc = nx;
  }
  return ev;
}

// blocks 0..511: per-node prep; 512..703: weight transposes
__global__ __launch_bounds__(128) void k_prep(
    const float* __restrict__ feat, const float* __restrict__ Wq,
    const float* __restrict__ Wk, const float* __restrict__ Wv,
    const float* __restrict__ Wek, const float* __restrict__ Wg,
    const float* __restrict__ We0, const float* __restrict__ We1,
    float* __restrict__ ws)
{
  const int blk = blockIdx.x, j = threadIdx.x;
  if (blk >= 512) {
    const int i = (blk - 512)*128 + j;
    ushort_t* W0T = (ushort_t*)(ws + WS_W0T);
    ushort_t* W1T = (ushort_t*)(ws + WS_W1T);
    if (i < 8192) {
      const int n = i >> 6, k = i & 63;
      W0T[n*64 + k] = f2b(We0[k*128 + n]);
    } else {
      const int t = i - 8192, n = t >> 7, k = t & 127;
      W1T[n*128 + k] = f2b(We1[k*128 + n]);
    }
    return;
  }
  const int r = blk;
  __shared__ float fr[128];
  __shared__ float qL[128];
  fr[j] = feat[r*128 + j];
  __syncthreads();
  float aq = 0.f, ak = 0.f, av = 0.f;
#pragma unroll 4
  for (int i = 0; i < 128; ++i) {
    const float f = fr[i];
    aq = fmaf(f, Wq[i*128 + j], aq);
    ak = fmaf(f, Wk[i*128 + j], ak);
    av = fmaf(f, Wv[i*128 + j], av);
  }
  ushort_t* knB = (ushort_t*)(ws + WS_KNB);
  ushort_t* vnT = (ushort_t*)(ws + WS_VNT);
  ushort_t* qnB = (ushort_t*)(ws + WS_QNB);
  knB[r*128 + j] = f2b(ak);
  vnT[j*512 + r] = f2b(av);
  qnB[r*128 + j] = f2b(0.25f * aq);
  qL[j] = aq;
  __syncthreads();
  ushort_t* A4 = (ushort_t*)(ws + WS_A4T) + r*1024;
  const float* wr = Wek + j*128;
#pragma unroll
  for (int h = 0; h < 8; ++h) {
    float acc = 0.f;
#pragma unroll
    for (int f = 0; f < 16; ++f)
      acc = fmaf(wr[16*h + f], qL[16*h + f], acc);
    A4[h*128 + j] = f2b(acc * 0.25f);
  }
  if (r == 0) {
    ushort_t* WgT = (ushort_t*)(ws + WS_WGT);
#pragma unroll
    for (int v = 0; v < 8; ++v)
      WgT[v*128 + j] = f2b(Wg[j*8 + v]);
  }
}

// LDS (40960 B exactly):
//   H1  @ 0      bf16[64][128] swz (Pb [16][64] swz + rscL f32[8] alias @0/@2048)
//   H2t @ 16384  bf16[128][64], chunk swz: elem(f,s) at ushort
//                f*64 + ((((s>>3) ^ (f&7) ^ ((f>>3)&7)) & 7)<<3) + (s&7)
//   Es  @ 32768  bf16[64][64] swz  (overlaid by lgT0@32768, lgT1@36864)
#define MFMA(a,b,c) __builtin_amdgcn_mfma_f32_16x16x32_bf16((a),(b),(c),0,0,0)

__global__ __launch_bounds__(512, 4) void k_edge17(
    const float* __restrict__ pos,
    const float* __restrict__ be0, const float* __restrict__ be1,
    float* __restrict__ ws)
{
  __shared__ __align__(16) char Lds[40960];
  ushort_t* H1   = (ushort_t*)(Lds);
  ushort_t* Pb   = (ushort_t*)(Lds);
  float*    rscL = (float*)(Lds + 2048);
  ushort_t* H2t  = (ushort_t*)(Lds + 16384);
  ushort_t* Es   = (ushort_t*)(Lds + 32768);
  float*    lgT0 = (float*)(Lds + 32768);
  float*    lgT1 = (float*)(Lds + 36864);

  const int tid = threadIdx.x;
  const int nw = tid >> 6, l = tid & 63;
  const int c = l & 15, g = l >> 4;
  const int b = blockIdx.x;
  const int r = b >> 2, quarter = b & 3;
  const int base = quarter * 128;

  const ushort_t* knB = (const ushort_t*)(ws + WS_KNB);
  const ushort_t* vnT = (const ushort_t*)(ws + WS_VNT);
  const ushort_t* qnB = (const ushort_t*)(ws + WS_QNB);
  const ushort_t* A4G = (const ushort_t*)(ws + WS_A4T) + r*1024;
  const ushort_t* WgG = (const ushort_t*)(ws + WS_WGT);
  const ushort_t* W0T = (const ushort_t*)(ws + WS_W0T);
  const ushort_t* W1T = (const ushort_t*)(ws + WS_W1T);

  const int ncol = nw*16 + c;
  const float be0v = be0[ncol], be1v = be1[ncol];
  const int m_lg = nw & 3, kh = nw >> 2;
  const int ncswz = ((ncol & 7) ^ ((ncol >> 3) & 7)) & 7;

  const float prx = pos[r*24 + nw*3 + 0];
  const float pry = pos[r*24 + nw*3 + 1];
  const float prz = pos[r*24 + nw*3 + 2];

  f32x4 bh = {0,0,0,0}, sna = {0,0,0,0};
  float avx = 0.f, avy = 0.f, avz = 0.f;
  float mrun = -1e30f, drun = 0.f;
  float ux, uy, uz;

  // prologue: geometry tile 0 -> Es
  {
    const int sg = base + l;
    const bf16x8 ev = radial_frag(pos[sg*24 + nw*3 + 0] - prx,
                                  pos[sg*24 + nw*3 + 1] - pry,
                                  pos[sg*24 + nw*3 + 2] - prz, ux, uy, uz);
    *(bf16x8*)(Es + l*64 + ((nw ^ (l&7))<<3)) = ev;
  }
  __syncthreads();

  for (int tile = 0; tile < 2; ++tile) {
    const int gbase = base + tile*64;

    float npx = 0.f, npy = 0.f, npz = 0.f;
    if (tile < 1) {
      const int sg = gbase + 64 + l;
      npx = pos[sg*24 + nw*3 + 0];
      npy = pos[sg*24 + nw*3 + 1];
      npz = pos[sg*24 + nw*3 + 2];
    }

    // ---- s0: L0 (Es @ We0 -> H1) ----
    {
      const bf16x8 w0f0 = *(const bf16x8*)(W0T + ncol*64 + g*8);
      const bf16x8 w0f1 = *(const bf16x8*)(W0T + ncol*64 + 32 + g*8);
#pragma unroll
      for (int m = 0; m < 4; ++m) {
        const int ra = m*16 + c;
        const bf16x8 e0 = *(const bf16x8*)(Es + ra*64 + (((g  ) ^ (ra&7))<<3));
        const bf16x8 e1 = *(const bf16x8*)(Es + ra*64 + (((4+g) ^ (ra&7))<<3));
        f32x4 acc = {0,0,0,0};
        acc = MFMA(e0, w0f0, acc);
        acc = MFMA(e1, w0f1, acc);
#pragma unroll
        for (int i = 0; i < 4; ++i) {
          const int row = m*16 + g*4 + i;
          H1[row*128 + (((ncol>>3) ^ (row&15))<<3) + (c&7)] =
              f2b(fsilu(acc[i] + be0v));
        }
      }
    }
    __syncthreads();  // B: H1 ready (Es consumed)

    // ---- s1: L1 (H1 @ We1) fused silu -> H2t (b64 writes) ----
#pragma unroll
    for (int m = 0; m < 4; ++m) {
      const int ra = m*16 + c;
      f32x4 acc = {0,0,0,0};
#pragma unroll
      for (int kb = 0; kb < 4; ++kb) {
        const bf16x8 af = *(const bf16x8*)(H1 + ra*128 + (((kb*4+g) ^ (ra&15))<<3));
        const bf16x8 wf = *(const bf16x8*)(W1T + ncol*128 + kb*32 + g*8);
        acc = MFMA(af, wf, acc);
      }
      short4v pk;
#pragma unroll
      for (int i = 0; i < 4; ++i)
        pk[i] = (short)f2b(fsilu(acc[i] + be1v));
      *(short4v*)(H2t + ncol*64 +
          ((((m*2 + (g>>1)) ^ ncswz) & 7)<<3) + (g&1)*4) = pk;
    }
    __syncthreads();  // C: H2t ready (H1 consumed; Pb window opens)

    // ---- s2: LG K=256 split -> lgT[ch][sender] ----
    {
      f32x4 lg = {0,0,0,0};
      if (kh == 0) {
        const int rb = m_lg*2 + (c>>3);   // sender>>3
        const int rl = c & 7;             // sender&7
        const ushort_t* ab = (c < 8) ? (A4G + c*128) : (WgG + (c-8)*128);
#pragma unroll
        for (int kb = 0; kb < 4; ++kb) {
          const int cc = (kb*4 + g) & 7;  // (f>>3)&7 for this frag
          bf16x8 bb;
#pragma unroll
          for (int j = 0; j < 8; ++j)
            bb[j] = (short)H2t[(kb*32 + g*8 + j)*64 +
                               (((rb ^ j ^ cc) & 7)<<3) + rl];
          const bf16x8 aw = *(const bf16x8*)(ab + kb*32 + g*8);
          lg = MFMA(aw, bb, lg);
        }
      } else {
        const int srow = gbase + m_lg*16 + c;
#pragma unroll
        for (int kb = 0; kb < 4; ++kb) {
          const bf16x8 bb = *(const bf16x8*)(knB + srow*128 + kb*32 + g*8);
          // masked-q A frag: q-block (kb*2 + (g>>1)) hits channel c only
          const bf16x8 qf = *(const bf16x8*)(qnB + r*128 + kb*32 + g*8);
          bf16x8 aw;
          const bool hit = (kb*2 + (g>>1)) == c;
#pragma unroll
          for (int j = 0; j < 8; ++j) aw[j] = hit ? qf[j] : (short)0;
          lg = MFMA(aw, bb, lg);
        }
      }
      float* lgW = kh ? lgT1 : lgT0;
#pragma unroll
      for (int i = 0; i < 4; ++i) {
        const int ch = g*4 + i;
        lgW[ch*64 + ((m_lg*16 + c) ^ (g<<4))] = lg[i];
      }
    }
    __syncthreads();  // S1: lgT ready

    // ---- s3: softmax (wave = head) + equivariant VALU accum ----
    {
      const int h = nw;
      const int kv = (h>>2)<<4;
      const int kg = ((8+h)>>2)<<4;
      float lgv = lgT0[h*64 + (l ^ kv)] + lgT1[h*64 + (l ^ kv)];
      const float gate = lgT0[(8+h)*64 + (l ^ kg)] + lgT1[(8+h)*64 + (l ^ kg)];
      if (gbase + l == r) lgv = -1e30f;
      float t = lgv;
      t = fmaxf(t, __shfl_xor(t, 1));
      t = fmaxf(t, __shfl_xor(t, 2));
      t = fmaxf(t, __shfl_xor(t, 4));
      t = fmaxf(t, __shfl_xor(t, 8));
      t = fmaxf(t, __shfl_xor(t, 16));
      t = fmaxf(t, __shfl_xor(t, 32));
      const float mnew = fmaxf(mrun, t);
      const float rsc = __expf(mrun - mnew);
      mrun = mnew;
      const float val = __expf(lgv - mnew);
      float wsm = val;
      wsm += __shfl_xor(wsm, 1);
      wsm += __shfl_xor(wsm, 2);
      wsm += __shfl_xor(wsm, 4);
      wsm += __shfl_xor(wsm, 8);
      wsm += __shfl_xor(wsm, 16);
      wsm += __shfl_xor(wsm, 32);
      drun = drun*rsc + wsm;
      const float ga = val * gate;
      Pb[h*64 + (((l>>3) ^ h)<<3) + (l&7)] = f2b(val);
      Pb[(8+h)*64 + (((l>>3) ^ h)<<3) + (l&7)] = f2b(ga);
      if (l == 0) rscL[h] = rsc;
      avx = avx*rsc + ga*ux;
      avy = avy*rsc + ga*uy;
      avz = avz*rsc + ga*uz;
    }
    __syncthreads();  // S2: Pb/rscL ready (lgT consumed; Es window opens)

    // ---- s4: rescale + P-MFMAs + geometry(t+1) -> Es ----
    {
      float rs[4];
#pragma unroll
      for (int i = 0; i < 4; ++i) rs[i] = rscL[(4*g + i) & 7];
#pragma unroll
      for (int i = 0; i < 4; ++i) { bh[i] *= rs[i]; sna[i] *= rs[i]; }
      const bf16x8 pa0 = *(const bf16x8*)(Pb + c*64 + (((g  ) ^ (c&7))<<3));
      const bf16x8 pa1 = *(const bf16x8*)(Pb + c*64 + (((4+g) ^ (c&7))<<3));
      bh = MFMA(pa0, *(const bf16x8*)(H2t + ncol*64 +
               ((((g  ) ^ ncswz) & 7)<<3)), bh);
      bh = MFMA(pa1, *(const bf16x8*)(H2t + ncol*64 +
               ((((4+g) ^ ncswz) & 7)<<3)), bh);
      const bf16x8 vnf0 = *(const bf16x8*)(vnT + ncol*512 + gbase + g*8);
      const bf16x8 vnf1 = *(const bf16x8*)(vnT + ncol*512 + gbase + 32 + g*8);
      sna = MFMA(pa0, vnf0, sna);
      sna = MFMA(pa1, vnf1, sna);
    }
    if (tile < 1) {
      const bf16x8 ev = radial_frag(npx - prx, npy - pry, npz - prz, ux, uy, uz);
      *(bf16x8*)(Es + l*64 + ((nw ^ (l&7))<<3)) = ev;
      __syncthreads();  // E: Es(t+1) ready; protects H1/Pb rewrite
    }
  }

  // ---- write partial state ----
  float* PSf = ws + WS_PS + b*PS_STRIDE;
  ushort_t* PSs = (ushort_t*)PSf;
  if (g < 2) {
#pragma unroll
    for (int i = 0; i < 4; ++i) {
      PSs[(4*g + i)*128 + ncol] = f2b(bh[i]);
      PSs[1024 + (4*g + i)*128 + ncol] = f2b(sna[i]);
    }
  }
  avx += __shfl_xor(avx, 1); avy += __shfl_xor(avy, 1); avz += __shfl_xor(avz, 1);
  avx += __shfl_xor(avx, 2); avy += __shfl_xor(avy, 2); avz += __shfl_xor(avz, 2);
  avx += __shfl_xor(avx, 4); avy += __shfl_xor(avy, 4); avz += __shfl_xor(avz, 4);
  avx += __shfl_xor(avx, 8); avy += __shfl_xor(avy, 8); avz += __shfl_xor(avz, 8);
  avx += __shfl_xor(avx,16); avy += __shfl_xor(avy,16); avz += __shfl_xor(avz,16);
  avx += __shfl_xor(avx,32); avy += __shfl_xor(avy,32); avz += __shfl_xor(avz,32);
  if (l == 0) {
    PSf[1024 + nw*3 + 0] = avx;
    PSf[1024 + nw*3 + 1] = avy;
    PSf[1024 + nw*3 + 2] = avz;
    PSf[1048 + nw] = mrun;
    PSf[1056 + nw] = drun;
  }
}

__global__ __launch_bounds__(128) void k_merge(
    const float* __restrict__ pos, const float* __restrict__ feat,
    const float* __restrict__ Wev,
    const float* __restrict__ Wo0, const float* __restrict__ bo0,
    const float* __restrict__ Wo1, const float* __restrict__ bo1,
    const float* __restrict__ Wo2, const float* __restrict__ bo2,
    const float* __restrict__ ws, float* __restrict__ out)
{
  const int r = blockIdx.x, j = threadIdx.x;
  __shared__ float Ss[32], Dh[8];
  __shared__ float BhC[1024];
  __shared__ float asB[128], o1[128], o2[128];
  const float* Pf[4];
  const ushort_t* Ps[4];
#pragma unroll
  for (int i = 0; i < 4; ++i) {
    Pf[i] = ws + WS_PS + (4*r + i)*PS_STRIDE;
    Ps[i] = (const ushort_t*)Pf[i];
  }
  if (j < 8) {
    float M = -1e30f;
#pragma unroll
    for (int i = 0; i < 4; ++i) M = fmaxf(M, Pf[i][1048 + j]);
    float D = 0.f;
#pragma unroll
    for (int i = 0; i < 4; ++i) {
      const float s = __expf(Pf[i][1048 + j] - M);
      Ss[i*8 + j] = s;
      D = fmaf(s, Pf[i][1056 + j], D);
    }
    Dh[j] = D;
  }
  __syncthreads();
#pragma unroll
  for (int h = 0; h < 8; ++h) {
    float acc = 0.f;
#pragma unroll
    for (int i = 0; i < 4; ++i)
      acc = fmaf(Ss[i*8 + h], b2f(Ps[i][h*128 + j]), acc);
    BhC[h*128 + j] = acc;
  }
  const int hh = j >> 4;
  float snj = 0.f;
#pragma unroll
  for (int i = 0; i < 4; ++i)
    snj = fmaf(Ss[i*8 + hh], b2f(Ps[i][1024 + hh*128 + j]), snj);
  if (j < 24) {
    const int v = j / 3;
    float avc = 0.f;
#pragma unroll
    for (int i = 0; i < 4; ++i)
      avc = fmaf(Ss[i*8 + v], Pf[i][1024 + j], avc);
    out[r*24 + j] = pos[r*24 + j]
        + 1.7320508076f * avc * __builtin_amdgcn_rcpf(Dh[v]);
  }
  __syncthreads();
  {
    float ev = 0.f;
#pragma unroll 4
    for (int m = 0; m < 128; ++m)
      ev = fmaf(BhC[hh*128 + m], Wev[m*128 + j], ev);
    asB[j] = (snj + ev) * __builtin_amdgcn_rcpf(Dh[hh]);
  }
  __syncthreads();
  {
    float acc = bo0[j];
#pragma unroll 4
    for (int i = 0; i < 128; ++i) acc = fmaf(asB[i], Wo0[i*128 + j], acc);
    o1[j] = fsilu(acc);
  }
  __syncthreads();
  {
    float acc = bo1[j];
#pragma unroll 4
    for (int i = 0; i < 128; ++i) acc = fmaf(o1[i], Wo1[i*128 + j], acc);
    o2[j] = fsilu(acc);
  }
  __syncthreads();
  {
    float acc = bo2[j];
#pragma unroll 4
    for (int i = 0; i < 128; ++i) acc = fmaf(o2[i], Wo2[i*128 + j], acc);
    out[12288 + r*128 + j] = feat[r*128 + j] + acc;
  }
}

extern "C" void kernel_launch(void* const* d_in, const int* in_sizes, int n_in,
                              void* d_out, int out_size, void* d_ws, size_t ws_size,
                              hipStream_t stream)
{
  const float* pos  = (const float*)d_in[0];
  const float* feat = (const float*)d_in[1];
  const float* We0  = (const float*)d_in[2];
  const float* be0  = (const float*)d_in[3];
  const float* We1  = (const float*)d_in[4];
  const float* be1  = (const float*)d_in[5];
  const float* Wq   = (const float*)d_in[6];
  const float* Wk   = (const float*)d_in[7];
  const float* Wek  = (const float*)d_in[8];
  const float* Wv   = (const float*)d_in[9];
  const float* Wev  = (const float*)d_in[10];
  const float* Wg   = (const float*)d_in[11];
  const float* Wo0  = (const float*)d_in[12];
  const float* bo0  = (const float*)d_in[13];
  const float* Wo1  = (const float*)d_in[14];
  const float* bo1  = (const float*)d_in[15];
  const float* Wo2  = (const float*)d_in[16];
  const float* bo2  = (const float*)d_in[17];
  float* ws  = (float*)d_ws;
  float* out = (float*)d_out;

  hipLaunchKernelGGL(k_prep, dim3(704), dim3(128), 0, stream,
                     feat, Wq, Wk, Wv, Wek, Wg, We0, We1, ws);
  hipLaunchKernelGGL(k_edge17, dim3(2048), dim3(512), 0, stream,
                     pos, be0, be1, ws);
  hipLaunchKernelGGL(k_merge, dim3(512), dim3(128), 0, stream,
                     pos, feat, Wev, Wo0, bo0, Wo1, bo1, Wo2, bo2, ws, out);
}